// Round 1
// baseline (559.591 us; speedup 1.0000x reference)
//
#include <hip/hip_runtime.h>

// Problem constants (fixed by the reference setup):
// B=16, C=64, NC=12500, N=50000, K=8, E=NC*K=100000
#define BATCH  16
#define CHAN   64
#define NCLIQ  12500
#define NODES  50000
#define NEDGE  100000

// ---------------- CSR build ----------------

__global__ void count_kernel(const int* __restrict__ node_ids,
                             int* __restrict__ counts, int E) {
    int e = blockIdx.x * blockDim.x + threadIdx.x;
    if (e < E) atomicAdd(&counts[node_ids[e]], 1);
}

// Local inclusive scan of 1024-element chunks; writes row_ptr[1+gid] (pre-offset)
// and per-block totals.
__global__ __launch_bounds__(1024) void scan_local(const int* __restrict__ counts,
                                                   int* __restrict__ row_ptr,
                                                   int* __restrict__ bsums, int n) {
    int tid  = threadIdx.x;
    int gid  = blockIdx.x * 1024 + tid;
    int lane = tid & 63, wid = tid >> 6;
    int v = (gid < n) ? counts[gid] : 0;
    // wave-64 inclusive scan
    for (int d = 1; d < 64; d <<= 1) {
        int t = __shfl_up(v, d, 64);
        if (lane >= d) v += t;
    }
    __shared__ int wsum[16];
    if (lane == 63) wsum[wid] = v;
    __syncthreads();
    if (tid < 16) {  // scan the 16 wave sums (all in wave 0)
        int s = wsum[tid];
        for (int d = 1; d < 16; d <<= 1) {
            int t = __shfl_up(s, d, 64);
            if (tid >= d) s += t;
        }
        wsum[tid] = s;
    }
    __syncthreads();
    int incl = v + (wid ? wsum[wid - 1] : 0);
    if (gid < n) row_ptr[1 + gid] = incl;
    if (tid == 1023) bsums[blockIdx.x] = incl;  // block total
}

// Add exclusive block prefix; each block (<=64 of them) reduces bsums itself.
__global__ __launch_bounds__(1024) void scan_add(int* __restrict__ row_ptr,
                                                 const int* __restrict__ bsums,
                                                 int n, int nblocks) {
    int tid = threadIdx.x;
    __shared__ int pref_sh;
    if (tid < 64) {
        int s = (tid < blockIdx.x && tid < nblocks) ? bsums[tid] : 0;
        for (int d = 1; d < 64; d <<= 1) s += __shfl_xor(s, d, 64);
        if (tid == 0) pref_sh = s;
    }
    __syncthreads();
    int prefix = pref_sh;
    int gid = blockIdx.x * 1024 + tid;
    if (gid < n) row_ptr[1 + gid] += prefix;
    if (gid == 0 && blockIdx.x == 0) row_ptr[0] = 0;
}

__global__ void fill_kernel(const int* __restrict__ node_ids,
                            const int* __restrict__ clique_ids,
                            const int* __restrict__ row_ptr,
                            int* __restrict__ cursor,   // zeroed counts, reused
                            int* __restrict__ cols, int E) {
    int e = blockIdx.x * blockDim.x + threadIdx.x;
    if (e < E) {
        int n = node_ids[e];
        int pos = atomicAdd(&cursor[n], 1);
        cols[row_ptr[n] + pos] = clique_ids[e];
    }
}

// ---------------- Main gather (write-once, coalesced float4 stores) ----------------

__global__ __launch_bounds__(256) void gather_kernel(const float* __restrict__ in,
                                                     const int* __restrict__ row_ptr,
                                                     const int* __restrict__ cols,
                                                     float* __restrict__ out) {
    int t  = blockIdx.x * 256 + threadIdx.x;      // [0, B*C*N/4)
    int n4 = t % (NODES / 4);
    int bc = t / (NODES / 4);
    const float* __restrict__ inrow = in + (size_t)bc * NCLIQ;  // 50 KB row, L1/L2-resident
    const int4 rp  = *reinterpret_cast<const int4*>(row_ptr + 4 * n4);
    const int  rp4 = row_ptr[4 * n4 + 4];
    float4 o;
    float v;
    v = 0.f; for (int i = rp.x; i < rp.y; ++i) v += inrow[cols[i]]; o.x = v;
    v = 0.f; for (int i = rp.y; i < rp.z; ++i) v += inrow[cols[i]]; o.y = v;
    v = 0.f; for (int i = rp.z; i < rp.w; ++i) v += inrow[cols[i]]; o.z = v;
    v = 0.f; for (int i = rp.w; i < rp4;  ++i) v += inrow[cols[i]]; o.w = v;
    *reinterpret_cast<float4*>(out + (size_t)bc * NODES + 4 * n4) = o;
}

// ---------------- launch ----------------

extern "C" void kernel_launch(void* const* d_in, const int* in_sizes, int n_in,
                              void* d_out, int out_size, void* d_ws, size_t ws_size,
                              hipStream_t stream) {
    const float* in         = (const float*)d_in[0];
    const int*   node_ids   = (const int*)d_in[1];
    const int*   clique_ids = (const int*)d_in[2];
    float*       out        = (float*)d_out;

    // Workspace layout (all int32): counts[N] | row_ptr[N+1] | cols[E] | bsums[64]
    int* ws      = (int*)d_ws;
    int* counts  = ws;                       // N ints
    int* row_ptr = counts + NODES;           // N+1 ints (byte off 200000, 16B-aligned)
    int* cols    = row_ptr + NODES + 1;      // E ints
    int* bsums   = cols + NEDGE;             // <=64 ints

    const int nblocks_scan = (NODES + 1023) / 1024;   // 49 (must be <= 64)

    hipMemsetAsync(counts, 0, NODES * sizeof(int), stream);
    count_kernel<<<(NEDGE + 255) / 256, 256, 0, stream>>>(node_ids, counts, NEDGE);
    scan_local<<<nblocks_scan, 1024, 0, stream>>>(counts, row_ptr, bsums, NODES);
    scan_add<<<nblocks_scan, 1024, 0, stream>>>(row_ptr, bsums, NODES, nblocks_scan);
    hipMemsetAsync(counts, 0, NODES * sizeof(int), stream);
    fill_kernel<<<(NEDGE + 255) / 256, 256, 0, stream>>>(node_ids, clique_ids,
                                                         row_ptr, counts, cols, NEDGE);
    gather_kernel<<<(BATCH * CHAN * (NODES / 4)) / 256, 256, 0, stream>>>(in, row_ptr,
                                                                          cols, out);
}

// Round 2
// 154.416 us; speedup vs baseline: 3.6239x; 3.6239x over previous
//
#include <hip/hip_runtime.h>

// Problem constants (fixed by the reference setup):
// B=16, C=64, NC=12500, N=50000, K=8, E=NC*K=100000
#define BATCH  16
#define CHAN   64
#define NCLIQ  12500
#define NODES  50000
#define NEDGE  100000
#define NGRP   64                                  // 1024 bc / 16 per group
#define NODEB  64                                  // nodes per gather block
#define NBLK   ((NODES + NODEB - 1) / NODEB)       // 782

// ---------------- CSR build ----------------

__global__ void count_kernel(const int* __restrict__ node_ids,
                             int* __restrict__ counts, int E) {
    int e = blockIdx.x * blockDim.x + threadIdx.x;
    if (e < E) atomicAdd(&counts[node_ids[e]], 1);
}

__global__ __launch_bounds__(1024) void scan_local(const int* __restrict__ counts,
                                                   int* __restrict__ row_ptr,
                                                   int* __restrict__ bsums, int n) {
    int tid  = threadIdx.x;
    int gid  = blockIdx.x * 1024 + tid;
    int lane = tid & 63, wid = tid >> 6;
    int v = (gid < n) ? counts[gid] : 0;
    for (int d = 1; d < 64; d <<= 1) {
        int t = __shfl_up(v, d, 64);
        if (lane >= d) v += t;
    }
    __shared__ int wsum[16];
    if (lane == 63) wsum[wid] = v;
    __syncthreads();
    if (tid < 16) {
        int s = wsum[tid];
        for (int d = 1; d < 16; d <<= 1) {
            int t = __shfl_up(s, d, 64);
            if (tid >= d) s += t;
        }
        wsum[tid] = s;
    }
    __syncthreads();
    int incl = v + (wid ? wsum[wid - 1] : 0);
    if (gid < n) row_ptr[1 + gid] = incl;
    if (tid == 1023) bsums[blockIdx.x] = incl;
}

__global__ __launch_bounds__(1024) void scan_add(int* __restrict__ row_ptr,
                                                 const int* __restrict__ bsums,
                                                 int n, int nblocks) {
    int tid = threadIdx.x;
    __shared__ int pref_sh;
    if (tid < 64) {
        int s = (tid < blockIdx.x && tid < nblocks) ? bsums[tid] : 0;
        for (int d = 1; d < 64; d <<= 1) s += __shfl_xor(s, d, 64);
        if (tid == 0) pref_sh = s;
    }
    __syncthreads();
    int prefix = pref_sh;
    int gid = blockIdx.x * 1024 + tid;
    if (gid < n) row_ptr[1 + gid] += prefix;
    if (gid == 0 && blockIdx.x == 0) row_ptr[0] = 0;
}

__global__ void fill_kernel(const int* __restrict__ node_ids,
                            const int* __restrict__ clique_ids,
                            const int* __restrict__ row_ptr,
                            int* __restrict__ cursor,
                            int* __restrict__ cols, int E) {
    int e = blockIdx.x * blockDim.x + threadIdx.x;
    if (e < E) {
        int n = node_ids[e];
        int pos = atomicAdd(&cursor[n], 1);
        cols[row_ptr[n] + pos] = clique_ids[e];
    }
}

// ---------------- 16-bc pack: in[bc][col] -> inP16[g][col][j], j=bc%16 ----------------
// Makes one clique column's 16 bc-values a contiguous 64B cache line.

__global__ __launch_bounds__(256) void pack_kernel(const float* __restrict__ in,
                                                   float* __restrict__ inP) {
    int col = blockIdx.x * 256 + threadIdx.x;
    int g   = blockIdx.y;
    if (col >= NCLIQ) return;
    float v[16];
    #pragma unroll
    for (int j = 0; j < 16; ++j)
        v[j] = in[(size_t)(g * 16 + j) * NCLIQ + col];   // coalesced per j
    float4* dst = reinterpret_cast<float4*>(inP + ((size_t)g * NCLIQ + col) * 16);
    #pragma unroll
    for (int q = 0; q < 4; ++q)
        dst[q] = make_float4(v[4 * q], v[4 * q + 1], v[4 * q + 2], v[4 * q + 3]);
}

// ---------------- Main gather: 4 lanes per node, float4 per lane ----------------
// Wave = 16 nodes x 4 quarters; every fetched 64B line of inP16 is fully used.
// Block decode keeps only 8 groups active device-wide (one per XCD with the
// usual round-robin mapping) so inP16 re-reads stay L2-resident.

__global__ __launch_bounds__(256) void gather16_kernel(const float* __restrict__ inP,
                                                       const int* __restrict__ row_ptr,
                                                       const int* __restrict__ cols,
                                                       float* __restrict__ out) {
    int b     = blockIdx.x;
    int k     = b & 7;
    int r     = b >> 3;
    int nb    = r % NBLK;
    int phase = r / NBLK;
    int g     = phase * 8 + k;        // group processed start-to-finish per XCD
    int tid   = threadIdx.x;
    int n     = nb * NODEB + (tid >> 2);
    int q     = tid & 3;
    if (n >= NODES) return;
    int r0 = row_ptr[n], r1 = row_ptr[n + 1];
    float4 a = make_float4(0.f, 0.f, 0.f, 0.f);
    const float* __restrict__ gbase = inP + (size_t)g * NCLIQ * 16 + q * 4;
    for (int i = r0; i < r1; ++i) {
        int col = cols[i];                       // broadcast across the 4-lane group
        const float4 p = *reinterpret_cast<const float4*>(gbase + (size_t)col * 16);
        a.x += p.x; a.y += p.y; a.z += p.z; a.w += p.w;
    }
    size_t base = (size_t)(g * 16 + q * 4) * NODES + n;
    out[base]                  = a.x;            // each plane coalesced across lanes
    out[base + NODES]          = a.y;
    out[base + 2 * (size_t)NODES] = a.z;
    out[base + 3 * (size_t)NODES] = a.w;
}

// ---------------- R0 fallback gather (used only if ws too small) ----------------

__global__ __launch_bounds__(256) void gather_kernel(const float* __restrict__ in,
                                                     const int* __restrict__ row_ptr,
                                                     const int* __restrict__ cols,
                                                     float* __restrict__ out) {
    int t  = blockIdx.x * 256 + threadIdx.x;
    int n4 = t % (NODES / 4);
    int bc = t / (NODES / 4);
    const float* __restrict__ inrow = in + (size_t)bc * NCLIQ;
    const int4 rp  = *reinterpret_cast<const int4*>(row_ptr + 4 * n4);
    const int  rp4 = row_ptr[4 * n4 + 4];
    float4 o;
    float v;
    v = 0.f; for (int i = rp.x; i < rp.y; ++i) v += inrow[cols[i]]; o.x = v;
    v = 0.f; for (int i = rp.y; i < rp.z; ++i) v += inrow[cols[i]]; o.y = v;
    v = 0.f; for (int i = rp.z; i < rp.w; ++i) v += inrow[cols[i]]; o.z = v;
    v = 0.f; for (int i = rp.w; i < rp4;  ++i) v += inrow[cols[i]]; o.w = v;
    *reinterpret_cast<float4*>(out + (size_t)bc * NODES + 4 * n4) = o;
}

// ---------------- launch ----------------

extern "C" void kernel_launch(void* const* d_in, const int* in_sizes, int n_in,
                              void* d_out, int out_size, void* d_ws, size_t ws_size,
                              hipStream_t stream) {
    const float* in         = (const float*)d_in[0];
    const int*   node_ids   = (const int*)d_in[1];
    const int*   clique_ids = (const int*)d_in[2];
    float*       out        = (float*)d_out;

    const size_t PACK_FLOATS = (size_t)NGRP * NCLIQ * 16;   // 12.8M floats = 51.2 MB
    const size_t need_packed = (PACK_FLOATS + NODES + NODES + 1 + NEDGE + 64) * 4;

    if (ws_size >= need_packed) {
        float* inP     = (float*)d_ws;
        int*   counts  = (int*)(inP + PACK_FLOATS);
        int*   row_ptr = counts + NODES;
        int*   cols    = row_ptr + NODES + 1;
        int*   bsums   = cols + NEDGE;
        const int nblocks_scan = (NODES + 1023) / 1024;   // 49

        hipMemsetAsync(counts, 0, NODES * sizeof(int), stream);
        count_kernel<<<(NEDGE + 255) / 256, 256, 0, stream>>>(node_ids, counts, NEDGE);
        scan_local<<<nblocks_scan, 1024, 0, stream>>>(counts, row_ptr, bsums, NODES);
        scan_add<<<nblocks_scan, 1024, 0, stream>>>(row_ptr, bsums, NODES, nblocks_scan);
        hipMemsetAsync(counts, 0, NODES * sizeof(int), stream);
        fill_kernel<<<(NEDGE + 255) / 256, 256, 0, stream>>>(node_ids, clique_ids,
                                                             row_ptr, counts, cols, NEDGE);
        pack_kernel<<<dim3((NCLIQ + 255) / 256, NGRP), 256, 0, stream>>>(in, inP);
        gather16_kernel<<<NGRP * NBLK, 256, 0, stream>>>(inP, row_ptr, cols, out);
    } else {
        int* ws      = (int*)d_ws;
        int* counts  = ws;
        int* row_ptr = counts + NODES;
        int* cols    = row_ptr + NODES + 1;
        int* bsums   = cols + NEDGE;
        const int nblocks_scan = (NODES + 1023) / 1024;

        hipMemsetAsync(counts, 0, NODES * sizeof(int), stream);
        count_kernel<<<(NEDGE + 255) / 256, 256, 0, stream>>>(node_ids, counts, NEDGE);
        scan_local<<<nblocks_scan, 1024, 0, stream>>>(counts, row_ptr, bsums, NODES);
        scan_add<<<nblocks_scan, 1024, 0, stream>>>(row_ptr, bsums, NODES, nblocks_scan);
        hipMemsetAsync(counts, 0, NODES * sizeof(int), stream);
        fill_kernel<<<(NEDGE + 255) / 256, 256, 0, stream>>>(node_ids, clique_ids,
                                                             row_ptr, counts, cols, NEDGE);
        gather_kernel<<<(BATCH * CHAN * (NODES / 4)) / 256, 256, 0, stream>>>(in, row_ptr,
                                                                              cols, out);
    }
}

// Round 3
// 130.582 us; speedup vs baseline: 4.2854x; 1.1825x over previous
//
#include <hip/hip_runtime.h>

// Problem constants (fixed by the reference setup):
// B=16, C=64, NC=12500, N=50000, K=8, E=NC*K=100000
#define BATCH  16
#define CHAN   64
#define NCLIQ  12500
#define NODES  50000
#define NEDGE  100000
#define NGRP   64                                  // 1024 bc / 16 per group
#define NODEB  64                                  // nodes per gather block
#define NBLK   ((NODES + NODEB - 1) / NODEB)       // 782

#define CNT_BLOCKS    ((NEDGE + 255) / 256)        // 391
#define PACK_BLOCKS_X ((NCLIQ + 255) / 256)        // 49
#define PACK_BLOCKS   (PACK_BLOCKS_X * NGRP)       // 3136

// ---------------- zero counts (replaces pathological hipMemsetAsync) ----------------

__global__ __launch_bounds__(256) void zero_counts(int4* __restrict__ counts4) {
    int t = blockIdx.x * 256 + threadIdx.x;
    if (t < NODES / 4) counts4[t] = make_int4(0, 0, 0, 0);
}

// ---------------- fused: edge counting + 16-bc input pack (independent work) --------
// blocks [0, CNT_BLOCKS): histogram node degrees.
// blocks [CNT_BLOCKS, CNT_BLOCKS+PACK_BLOCKS): in[bc][col] -> inP[g][col][j], j=bc%16
// (makes one clique column's 16 bc-values a contiguous 64B cache line).

__global__ __launch_bounds__(256) void count_pack(const int* __restrict__ node_ids,
                                                  int* __restrict__ counts,
                                                  const float* __restrict__ in,
                                                  float* __restrict__ inP) {
    int b   = blockIdx.x;
    int tid = threadIdx.x;
    if (b < CNT_BLOCKS) {
        int e = b * 256 + tid;
        if (e < NEDGE) atomicAdd(&counts[node_ids[e]], 1);
    } else {
        int pb  = b - CNT_BLOCKS;
        int g   = pb / PACK_BLOCKS_X;
        int col = (pb % PACK_BLOCKS_X) * 256 + tid;
        if (col < NCLIQ) {
            float v[16];
            #pragma unroll
            for (int j = 0; j < 16; ++j)
                v[j] = __builtin_nontemporal_load(in + (size_t)(g * 16 + j) * NCLIQ + col);
            float4* dst = reinterpret_cast<float4*>(inP + ((size_t)g * NCLIQ + col) * 16);
            #pragma unroll
            for (int q = 0; q < 4; ++q)
                dst[q] = make_float4(v[4 * q], v[4 * q + 1], v[4 * q + 2], v[4 * q + 3]);
        }
    }
}

// ---------------- scan: row_ptr = exclusive prefix of counts ----------------

__global__ __launch_bounds__(1024) void scan_local(const int* __restrict__ counts,
                                                   int* __restrict__ row_ptr,
                                                   int* __restrict__ bsums, int n) {
    int tid  = threadIdx.x;
    int gid  = blockIdx.x * 1024 + tid;
    int lane = tid & 63, wid = tid >> 6;
    int v = (gid < n) ? counts[gid] : 0;
    for (int d = 1; d < 64; d <<= 1) {
        int t = __shfl_up(v, d, 64);
        if (lane >= d) v += t;
    }
    __shared__ int wsum[16];
    if (lane == 63) wsum[wid] = v;
    __syncthreads();
    if (tid < 16) {
        int s = wsum[tid];
        for (int d = 1; d < 16; d <<= 1) {
            int t = __shfl_up(s, d, 64);
            if (tid >= d) s += t;
        }
        wsum[tid] = s;
    }
    __syncthreads();
    int incl = v + (wid ? wsum[wid - 1] : 0);
    if (gid < n) row_ptr[1 + gid] = incl;
    if (tid == 1023) bsums[blockIdx.x] = incl;
}

__global__ __launch_bounds__(1024) void scan_add(int* __restrict__ row_ptr,
                                                 const int* __restrict__ bsums,
                                                 int n, int nblocks) {
    int tid = threadIdx.x;
    __shared__ int pref_sh;
    if (tid < 64) {
        int s = (tid < blockIdx.x && tid < nblocks) ? bsums[tid] : 0;
        for (int d = 1; d < 64; d <<= 1) s += __shfl_xor(s, d, 64);
        if (tid == 0) pref_sh = s;
    }
    __syncthreads();
    int prefix = pref_sh;
    int gid = blockIdx.x * 1024 + tid;
    if (gid < n) row_ptr[1 + gid] += prefix;
    if (gid == 0 && blockIdx.x == 0) row_ptr[0] = 0;
}

// ---------------- fill: counts holds deg; atomicSub makes it a countdown cursor -----

__global__ void fill_kernel(const int* __restrict__ node_ids,
                            const int* __restrict__ clique_ids,
                            const int* __restrict__ row_ptr,
                            int* __restrict__ counts,
                            int* __restrict__ cols, int E) {
    int e = blockIdx.x * blockDim.x + threadIdx.x;
    if (e < E) {
        int n = node_ids[e];
        int pos = atomicAdd(&counts[n], -1) - 1;   // deg-1 .. 0, unique
        cols[row_ptr[n] + pos] = clique_ids[e];
    }
}

// ---------------- Main gather: 4 lanes per node, float4 per lane ----------------
// Wave = 16 nodes x 4 quarters; every fetched 64B line of inP is fully used.
// XCD-phase decode keeps 8 groups active device-wide -> inP slice L2-resident.
// Output is write-once: nontemporal stores keep the streaming 204.8 MB from
// evicting inP/cols/row_ptr out of L2.

__global__ __launch_bounds__(256) void gather16_kernel(const float* __restrict__ inP,
                                                       const int* __restrict__ row_ptr,
                                                       const int* __restrict__ cols,
                                                       float* __restrict__ out) {
    int b     = blockIdx.x;
    int k     = b & 7;
    int r     = b >> 3;
    int nb    = r % NBLK;
    int phase = r / NBLK;
    int g     = phase * 8 + k;
    int tid   = threadIdx.x;
    int n     = nb * NODEB + (tid >> 2);
    int q     = tid & 3;
    if (n >= NODES) return;
    int r0 = row_ptr[n], r1 = row_ptr[n + 1];
    float4 a = make_float4(0.f, 0.f, 0.f, 0.f);
    float4 a2 = make_float4(0.f, 0.f, 0.f, 0.f);
    const float* __restrict__ gbase = inP + (size_t)g * NCLIQ * 16 + q * 4;
    int i = r0;
    for (; i + 2 <= r1; i += 2) {                 // dual accumulators, independent loads
        int c0 = cols[i], c1 = cols[i + 1];
        const float4 p0 = *reinterpret_cast<const float4*>(gbase + (size_t)c0 * 16);
        const float4 p1 = *reinterpret_cast<const float4*>(gbase + (size_t)c1 * 16);
        a.x += p0.x;  a.y += p0.y;  a.z += p0.z;  a.w += p0.w;
        a2.x += p1.x; a2.y += p1.y; a2.z += p1.z; a2.w += p1.w;
    }
    if (i < r1) {
        int c0 = cols[i];
        const float4 p0 = *reinterpret_cast<const float4*>(gbase + (size_t)c0 * 16);
        a.x += p0.x; a.y += p0.y; a.z += p0.z; a.w += p0.w;
    }
    a.x += a2.x; a.y += a2.y; a.z += a2.z; a.w += a2.w;
    size_t base = (size_t)(g * 16 + q * 4) * NODES + n;
    __builtin_nontemporal_store(a.x, out + base);
    __builtin_nontemporal_store(a.y, out + base + NODES);
    __builtin_nontemporal_store(a.z, out + base + 2 * (size_t)NODES);
    __builtin_nontemporal_store(a.w, out + base + 3 * (size_t)NODES);
}

// ---------------- launch ----------------

extern "C" void kernel_launch(void* const* d_in, const int* in_sizes, int n_in,
                              void* d_out, int out_size, void* d_ws, size_t ws_size,
                              hipStream_t stream) {
    const float* in         = (const float*)d_in[0];
    const int*   node_ids   = (const int*)d_in[1];
    const int*   clique_ids = (const int*)d_in[2];
    float*       out        = (float*)d_out;

    const size_t PACK_FLOATS = (size_t)NGRP * NCLIQ * 16;   // 12.8M floats = 51.2 MB

    float* inP     = (float*)d_ws;
    int*   counts  = (int*)(inP + PACK_FLOATS);
    int*   row_ptr = counts + NODES;
    int*   cols    = row_ptr + NODES + 1;
    int*   bsums   = cols + NEDGE;
    const int nblocks_scan = (NODES + 1023) / 1024;   // 49 (<= 64)

    zero_counts<<<(NODES / 4 + 255) / 256, 256, 0, stream>>>((int4*)counts);
    count_pack<<<CNT_BLOCKS + PACK_BLOCKS, 256, 0, stream>>>(node_ids, counts, in, inP);
    scan_local<<<nblocks_scan, 1024, 0, stream>>>(counts, row_ptr, bsums, NODES);
    scan_add<<<nblocks_scan, 1024, 0, stream>>>(row_ptr, bsums, NODES, nblocks_scan);
    fill_kernel<<<CNT_BLOCKS, 256, 0, stream>>>(node_ids, clique_ids,
                                                row_ptr, counts, cols, NEDGE);
    gather16_kernel<<<NGRP * NBLK, 256, 0, stream>>>(inP, row_ptr, cols, out);
}